// Round 1
// baseline (350.338 us; speedup 1.0000x reference)
//
#include <hip/hip_runtime.h>
#include <cstdint>
#include <cstddef>

#define H 8
#define DH 128
#define RNK 32
#define SS 1024
#define BB 8
#define DD 1024

typedef __bf16 bf16x8 __attribute__((ext_vector_type(8)));
typedef float f32x4 __attribute__((ext_vector_type(4)));

__device__ __forceinline__ unsigned short f2bf(float f) {
  unsigned int u = __builtin_bit_cast(unsigned int, f);
  return (unsigned short)((u + 0x7FFFu + ((u >> 16) & 1u)) >> 16);
}

// Swizzled LDS fragment read: 8 contiguous bf16 at (row, kbyte), row-XOR swizzle
__device__ __forceinline__ bf16x8 lds_frag(const unsigned short* base, int row, int kbyte, int rowbytes) {
  int off = row * rowbytes + kbyte;
  off ^= (row & 7) << 4;
  return *reinterpret_cast<const bf16x8*>(reinterpret_cast<const char*>(base) + off);
}

// ---------------- Kernel A: W = U @ V per (proj, head), f32 -> bf16 ----------------
__global__ __launch_bounds__(256) void wcomb_kernel(
    const float* __restrict__ Uq, const float* __restrict__ Vq,
    const float* __restrict__ Uk, const float* __restrict__ Vk,
    const float* __restrict__ Uv, const float* __restrict__ Vv,
    unsigned short* __restrict__ Wc) {
  const int p = blockIdx.x / H, h = blockIdx.x % H;
  const float* U = (p == 0) ? Uq : ((p == 1) ? Uk : Uv);
  const float* V = (p == 0) ? Vq : ((p == 1) ? Vk : Vv);
  U += (size_t)h * DH * RNK;
  V += (size_t)h * RNK * DH;
  __shared__ float Vl[RNK * DH];
  for (int i = threadIdx.x; i < RNK * DH; i += 256) Vl[i] = V[i];
  __syncthreads();
  const int dout = threadIdx.x >> 1;
  const int di0 = (threadIdx.x & 1) * 64;
  float Ur[RNK];
#pragma unroll
  for (int r = 0; r < RNK; ++r) Ur[r] = U[dout * RNK + r];
  unsigned short* outp = Wc + ((size_t)(p * H + h) * DH + dout) * DH + di0;
  for (int di = 0; di < 64; ++di) {
    float acc = 0.f;
#pragma unroll
    for (int r = 0; r < RNK; ++r) acc += Ur[r] * Vl[r * DH + di0 + di];
    outp[di] = f2bf(acc);
  }
}

// ---------------- Kernel B: QKV projection GEMM ----------------
// p<2 (Q,K): A=W (rows d_out), B=X (cols s)  -> vectorized stores to [b,h,s,d]
// p==2 (V):  A=X (rows s),    B=W (cols d)  -> vectorized stores to V^T [b,h,d,s]
__global__ __launch_bounds__(256) void proj_kernel(
    const float* __restrict__ x, const unsigned short* __restrict__ Wc,
    const float* __restrict__ bq, const float* __restrict__ bk, const float* __restrict__ bv,
    unsigned short* __restrict__ Qp, unsigned short* __restrict__ Kp, unsigned short* __restrict__ Vt) {
  const int mt = blockIdx.x;  // 64 token tiles of 128
  const int h  = blockIdx.y;  // 8
  const int p  = blockIdx.z;  // 3
  const int tid = threadIdx.x;
  const int wid = tid >> 6;
  const int lane = tid & 63;
  const int lr = lane & 15, lk = lane >> 4;

  __shared__ unsigned short xs[128 * 128];
  __shared__ unsigned short wsl[128 * 128];

  { // stage x tile: 128 tokens x 128 dims, f32 -> bf16, swizzled
    const float* xb = x + (size_t)(mt * 128) * DD + h * DH;
    const int c4 = tid & 31, r0 = tid >> 5;
#pragma unroll
    for (int i = 0; i < 16; ++i) {
      const int r = r0 + i * 8;
      const float4 v = *reinterpret_cast<const float4*>(xb + (size_t)r * DD + c4 * 4);
      int off = r * 256 + c4 * 8; off ^= (r & 7) << 4;
      ushort4 o;
      o.x = f2bf(v.x); o.y = f2bf(v.y); o.z = f2bf(v.z); o.w = f2bf(v.w);
      *reinterpret_cast<ushort4*>(reinterpret_cast<char*>(xs) + off) = o;
    }
  }
  { // stage W tile (already bf16), swizzled
    const unsigned short* wg = Wc + ((size_t)(p * H + h) << 14);
    const int c8 = tid & 15, r0 = tid >> 4;
#pragma unroll
    for (int i = 0; i < 8; ++i) {
      const int r = r0 + i * 16;
      const uint4 v = *reinterpret_cast<const uint4*>(wg + r * 128 + c8 * 8);
      int off = r * 256 + c8 * 16; off ^= (r & 7) << 4;
      *reinterpret_cast<uint4*>(reinterpret_cast<char*>(wsl) + off) = v;
    }
  }
  __syncthreads();

  f32x4 acc[2][8];
#pragma unroll
  for (int m = 0; m < 2; ++m)
#pragma unroll
    for (int n = 0; n < 8; ++n) acc[m][n] = {0.f, 0.f, 0.f, 0.f};

  if (p < 2) {
#pragma unroll
    for (int kk = 0; kk < 4; ++kk) {
      bf16x8 a[2], bfr[8];
#pragma unroll
      for (int m = 0; m < 2; ++m) a[m] = lds_frag(wsl, wid * 32 + m * 16 + lr, kk * 64 + lk * 16, 256);
#pragma unroll
      for (int n = 0; n < 8; ++n) bfr[n] = lds_frag(xs, n * 16 + lr, kk * 64 + lk * 16, 256);
#pragma unroll
      for (int m = 0; m < 2; ++m)
#pragma unroll
        for (int n = 0; n < 8; ++n)
          acc[m][n] = __builtin_amdgcn_mfma_f32_16x16x32_bf16(a[m], bfr[n], acc[m][n], 0, 0, 0);
    }
    const float* bias = ((p == 0) ? bq : bk) + h * DH;
    unsigned short* dst = ((p == 0) ? Qp : Kp);
#pragma unroll
    for (int m = 0; m < 2; ++m) {
      const int d0 = wid * 32 + m * 16 + lk * 4;
      const float4 bb = *reinterpret_cast<const float4*>(bias + d0);
#pragma unroll
      for (int n = 0; n < 8; ++n) {
        const int tok = mt * 128 + n * 16 + lr;
        const int b = tok >> 10, si = tok & 1023;
        ushort4 o;
        o.x = f2bf(acc[m][n][0] + bb.x);
        o.y = f2bf(acc[m][n][1] + bb.y);
        o.z = f2bf(acc[m][n][2] + bb.z);
        o.w = f2bf(acc[m][n][3] + bb.w);
        *reinterpret_cast<ushort4*>(dst + ((size_t)(b * H + h) * SS + si) * DH + d0) = o;
      }
    }
  } else {
#pragma unroll
    for (int kk = 0; kk < 4; ++kk) {
      bf16x8 a[2], bfr[8];
#pragma unroll
      for (int m = 0; m < 2; ++m) a[m] = lds_frag(xs, wid * 32 + m * 16 + lr, kk * 64 + lk * 16, 256);
#pragma unroll
      for (int n = 0; n < 8; ++n) bfr[n] = lds_frag(wsl, n * 16 + lr, kk * 64 + lk * 16, 256);
#pragma unroll
      for (int m = 0; m < 2; ++m)
#pragma unroll
        for (int n = 0; n < 8; ++n)
          acc[m][n] = __builtin_amdgcn_mfma_f32_16x16x32_bf16(a[m], bfr[n], acc[m][n], 0, 0, 0);
    }
    const float* bias = bv + h * DH;
#pragma unroll
    for (int n = 0; n < 8; ++n) {
      const int d = n * 16 + lr;
      const float bb = bias[d];
#pragma unroll
      for (int m = 0; m < 2; ++m) {
        const int tok0 = mt * 128 + wid * 32 + m * 16 + lk * 4;
        const int b = tok0 >> 10, s0 = tok0 & 1023;
        ushort4 o;
        o.x = f2bf(acc[m][n][0] + bb);
        o.y = f2bf(acc[m][n][1] + bb);
        o.z = f2bf(acc[m][n][2] + bb);
        o.w = f2bf(acc[m][n][3] + bb);
        *reinterpret_cast<ushort4*>(Vt + ((size_t)(b * H + h) * DH + d) * SS + s0) = o;
      }
    }
  }
}

// ---------------- Kernel C: flash attention ----------------
__global__ __launch_bounds__(256) void attn_kernel(
    const unsigned short* __restrict__ Qp, const unsigned short* __restrict__ Kp,
    const unsigned short* __restrict__ Vt, float* __restrict__ outp) {
  const int qt = blockIdx.x;   // 8 q-tiles of 128
  const int bh = blockIdx.y;   // 64 (b*H + h)
  const int b = bh >> 3, h = bh & 7;
  const int tid = threadIdx.x, wid = tid >> 6, lane = tid & 63;
  const int lr = lane & 15, lk = lane >> 4;

  __shared__ unsigned short ks[64 * 128];
  __shared__ unsigned short vts[128 * 64];
  __shared__ unsigned short ps[4][32 * 64];

  // Q fragments held in registers: wave owns 32 q-rows
  bf16x8 qa[2][4];
  {
    const unsigned short* Qg = Qp + (size_t)bh * (SS * DH) + (size_t)(qt * 128 + wid * 32) * DH;
#pragma unroll
    for (int m = 0; m < 2; ++m)
#pragma unroll
      for (int kk = 0; kk < 4; ++kk)
        qa[m][kk] = *reinterpret_cast<const bf16x8*>(Qg + (m * 16 + lr) * DH + kk * 32 + lk * 8);
  }

  const unsigned short* Kg = Kp + (size_t)bh * (SS * DH);
  const unsigned short* Vg = Vt + (size_t)bh * (DH * SS);

  f32x4 oacc[2][8];
  float mrow[2][4], lrow[2][4];
#pragma unroll
  for (int m = 0; m < 2; ++m) {
#pragma unroll
    for (int n = 0; n < 8; ++n) oacc[m][n] = {0.f, 0.f, 0.f, 0.f};
#pragma unroll
    for (int r = 0; r < 4; ++r) { mrow[m][r] = -1e30f; lrow[m][r] = 0.f; }
  }

  const float cs = 0.088388347648318447f * 1.4426950408889634f;  // 1/sqrt(128) * log2(e)

  for (int kt = 0; kt < 16; ++kt) {
    __syncthreads();  // previous PV reads of ks/vts done
    { // stage K tile: 64 rows(k) x 128(d), swizzled
      const int c8 = tid & 15, r0 = tid >> 4;
#pragma unroll
      for (int i = 0; i < 4; ++i) {
        const int r = r0 + i * 16;
        const uint4 v = *reinterpret_cast<const uint4*>(Kg + (size_t)(kt * 64 + r) * DH + c8 * 8);
        int off = r * 256 + c8 * 16; off ^= (r & 7) << 4;
        *reinterpret_cast<uint4*>(reinterpret_cast<char*>(ks) + off) = v;
      }
    }
    { // stage V^T tile: 128 rows(d) x 64(k), swizzled
      const int c8 = tid & 7, r0 = tid >> 3;
#pragma unroll
      for (int i = 0; i < 4; ++i) {
        const int r = r0 + i * 32;
        const uint4 v = *reinterpret_cast<const uint4*>(Vg + (size_t)r * SS + kt * 64 + c8 * 8);
        int off = r * 128 + c8 * 16; off ^= (r & 7) << 4;
        *reinterpret_cast<uint4*>(reinterpret_cast<char*>(vts) + off) = v;
      }
    }
    __syncthreads();

    // S = Q K^T  (rows q, cols k-tile of 64)
    f32x4 sacc[2][4];
#pragma unroll
    for (int m = 0; m < 2; ++m)
#pragma unroll
      for (int n = 0; n < 4; ++n) sacc[m][n] = {0.f, 0.f, 0.f, 0.f};
#pragma unroll
    for (int kk = 0; kk < 4; ++kk) {
      bf16x8 bfr[4];
#pragma unroll
      for (int n = 0; n < 4; ++n) bfr[n] = lds_frag(ks, n * 16 + lr, kk * 64 + lk * 16, 256);
#pragma unroll
      for (int m = 0; m < 2; ++m)
#pragma unroll
        for (int n = 0; n < 4; ++n)
          sacc[m][n] = __builtin_amdgcn_mfma_f32_16x16x32_bf16(qa[m][kk], bfr[n], sacc[m][n], 0, 0, 0);
    }

    // online softmax (row = q lives across 16 lanes sharing lk)
#pragma unroll
    for (int m = 0; m < 2; ++m)
#pragma unroll
      for (int r = 0; r < 4; ++r) {
        float mx = fmaxf(fmaxf(sacc[m][0][r], sacc[m][1][r]), fmaxf(sacc[m][2][r], sacc[m][3][r]));
#pragma unroll
        for (int msk = 1; msk < 16; msk <<= 1) mx = fmaxf(mx, __shfl_xor(mx, msk));
        const float m2 = mx * cs;
        const float mnew = fmaxf(mrow[m][r], m2);
        const float alpha = exp2f(mrow[m][r] - mnew);
        mrow[m][r] = mnew;
        float rs = 0.f;
#pragma unroll
        for (int n = 0; n < 4; ++n) {
          const float pv = exp2f(sacc[m][n][r] * cs - mnew);
          sacc[m][n][r] = pv;
          rs += pv;
        }
#pragma unroll
        for (int msk = 1; msk < 16; msk <<= 1) rs += __shfl_xor(rs, msk);
        lrow[m][r] = lrow[m][r] * alpha + rs;
#pragma unroll
        for (int n = 0; n < 8; ++n) oacc[m][n][r] *= alpha;
      }

    // write P (bf16) to wave-private swizzled LDS
    unsigned short* pw = ps[wid];
#pragma unroll
    for (int m = 0; m < 2; ++m)
#pragma unroll
      for (int n = 0; n < 4; ++n)
#pragma unroll
        for (int r = 0; r < 4; ++r) {
          const int row = m * 16 + lk * 4 + r;
          int off = row * 128 + (n * 16 + lr) * 2; off ^= (row & 7) << 4;
          *reinterpret_cast<unsigned short*>(reinterpret_cast<char*>(pw) + off) = f2bf(sacc[m][n][r]);
        }
    __syncthreads();  // also covers cross-lane P visibility

    // O += P V   (A = P rows q, B = V^T rows d)
#pragma unroll
    for (int kk = 0; kk < 2; ++kk) {
      bf16x8 pa[2];
#pragma unroll
      for (int m = 0; m < 2; ++m) pa[m] = lds_frag(pw, m * 16 + lr, kk * 64 + lk * 16, 128);
#pragma unroll
      for (int n = 0; n < 8; ++n) {
        const bf16x8 bv8 = lds_frag(vts, n * 16 + lr, kk * 64 + lk * 16, 128);
#pragma unroll
        for (int m = 0; m < 2; ++m)
          oacc[m][n] = __builtin_amdgcn_mfma_f32_16x16x32_bf16(pa[m], bv8, oacc[m][n], 0, 0, 0);
      }
    }
  }

  // epilogue: normalize and store f32
#pragma unroll
  for (int m = 0; m < 2; ++m)
#pragma unroll
    for (int r = 0; r < 4; ++r) {
      const float inv = 1.f / lrow[m][r];
      const int srow = qt * 128 + wid * 32 + m * 16 + lk * 4 + r;
      float* og = outp + ((size_t)b * SS + srow) * DD + h * DH;
#pragma unroll
      for (int n = 0; n < 8; ++n) og[n * 16 + lr] = oacc[m][n][r] * inv;
    }
}

extern "C" void kernel_launch(void* const* d_in, const int* in_sizes, int n_in,
                              void* d_out, int out_size, void* d_ws, size_t ws_size,
                              hipStream_t stream) {
  const float* x  = (const float*)d_in[0];
  const float* Uq = (const float*)d_in[1];
  const float* Vq = (const float*)d_in[2];
  const float* bq = (const float*)d_in[3];
  const float* Uk = (const float*)d_in[4];
  const float* Vk = (const float*)d_in[5];
  const float* bk = (const float*)d_in[6];
  const float* Uv = (const float*)d_in[7];
  const float* Vv = (const float*)d_in[8];
  const float* bv = (const float*)d_in[9];
  float* outp = (float*)d_out;

  unsigned short* Wc = (unsigned short*)d_ws;                     // 3*8*128*128 bf16
  unsigned short* Qp = Wc + (size_t)3 * H * DH * DH;              // [b,h,s,d] bf16
  unsigned short* Kp = Qp + (size_t)BB * H * SS * DH;             // [b,h,s,d] bf16
  unsigned short* Vt = Kp + (size_t)BB * H * SS * DH;             // [b,h,d,s] bf16

  wcomb_kernel<<<dim3(24), dim3(256), 0, stream>>>(Uq, Vq, Uk, Vk, Uv, Vv, Wc);
  proj_kernel<<<dim3(64, 8, 3), dim3(256), 0, stream>>>(x, Wc, bq, bk, bv, Qp, Kp, Vt);
  attn_kernel<<<dim3(8, 64), dim3(256), 0, stream>>>(Qp, Kp, Vt, outp);
}

// Round 2
// 260.820 us; speedup vs baseline: 1.3432x; 1.3432x over previous
//
#include <hip/hip_runtime.h>
#include <cstdint>
#include <cstddef>

#define H 8
#define DH 128
#define RNK 32
#define SS 1024
#define BB 8
#define DD 1024

typedef __bf16 bf16x8 __attribute__((ext_vector_type(8)));
typedef float f32x4 __attribute__((ext_vector_type(4)));

// log2(e)/sqrt(DH): folded into Wq and bq so QK^T is already in log2 domain.
#define QSCALE (1.4426950408889634f / 11.313708498984761f)

__device__ __forceinline__ unsigned short f2bf(float f) {
  unsigned int u = __builtin_bit_cast(unsigned int, f);
  return (unsigned short)((u + 0x7FFFu + ((u >> 16) & 1u)) >> 16);
}

__device__ __forceinline__ unsigned int cvtpk_bf16(float lo, float hi) {
  unsigned int r;
  asm("v_cvt_pk_bf16_f32 %0, %1, %2" : "=v"(r) : "v"(lo), "v"(hi));
  return r;
}

// Swizzled LDS fragment read: 8 contiguous bf16 at (row, kbyte), row-XOR swizzle
__device__ __forceinline__ bf16x8 lds_frag(const unsigned short* base, int row, int kbyte, int rowbytes) {
  int off = row * rowbytes + kbyte;
  off ^= (row & 7) << 4;
  return *reinterpret_cast<const bf16x8*>(reinterpret_cast<const char*>(base) + off);
}

// ---------------- Kernel A: W = U @ V per (proj, head), f32 -> bf16 ----------------
// Q-projection weights are pre-scaled by QSCALE (log2e/sqrt(DH)).
__global__ __launch_bounds__(256) void wcomb_kernel(
    const float* __restrict__ Uq, const float* __restrict__ Vq,
    const float* __restrict__ Uk, const float* __restrict__ Vk,
    const float* __restrict__ Uv, const float* __restrict__ Vv,
    unsigned short* __restrict__ Wc) {
  const int p = blockIdx.x / H, h = blockIdx.x % H;
  const float* U = (p == 0) ? Uq : ((p == 1) ? Uk : Uv);
  const float* V = (p == 0) ? Vq : ((p == 1) ? Vk : Vv);
  const float scale = (p == 0) ? QSCALE : 1.0f;
  U += (size_t)h * DH * RNK;
  V += (size_t)h * RNK * DH;
  __shared__ float Vl[RNK * DH];
  for (int i = threadIdx.x; i < RNK * DH; i += 256) Vl[i] = V[i];
  __syncthreads();
  const int dout = threadIdx.x >> 1;
  const int di0 = (threadIdx.x & 1) * 64;
  float Ur[RNK];
#pragma unroll
  for (int r = 0; r < RNK; ++r) Ur[r] = U[dout * RNK + r];
  unsigned short* outp = Wc + ((size_t)(p * H + h) * DH + dout) * DH + di0;
  for (int di = 0; di < 64; ++di) {
    float acc = 0.f;
#pragma unroll
    for (int r = 0; r < RNK; ++r) acc += Ur[r] * Vl[r * DH + di0 + di];
    outp[di] = f2bf(acc * scale);
  }
}

// ---------------- Kernel B: fused QKV projection ----------------
// One block per (token-tile 128, head): x staged in LDS once (bf16, swizzled);
// W fragments read direct from global (768 KB total, L2-resident).
// p<2 (Q,K): A=W (rows d_out), B=X (cols s)  -> vectorized stores to [b,h,s,d]
// p==2 (V):  A=X (rows s),    B=W (cols d)  -> vectorized stores to V^T [b,h,d,s]
__global__ __launch_bounds__(256, 2) void proj_kernel(
    const float* __restrict__ x, const unsigned short* __restrict__ Wc,
    const float* __restrict__ bq, const float* __restrict__ bk, const float* __restrict__ bv,
    unsigned short* __restrict__ Qp, unsigned short* __restrict__ Kp, unsigned short* __restrict__ Vt) {
  const int mt = blockIdx.x;  // 64 token tiles of 128
  const int h  = blockIdx.y;  // 8
  const int tid = threadIdx.x;
  const int wid = tid >> 6;
  const int lane = tid & 63;
  const int lr = lane & 15, lk = lane >> 4;

  __shared__ unsigned short xs[128 * 128];

  { // stage x tile: 128 tokens x 128 dims, f32 -> bf16, swizzled
    const float* xb = x + (size_t)(mt * 128) * DD + h * DH;
    const int c4 = tid & 31, r0 = tid >> 5;
#pragma unroll
    for (int i = 0; i < 16; ++i) {
      const int r = r0 + i * 8;
      const float4 v = *reinterpret_cast<const float4*>(xb + (size_t)r * DD + c4 * 4);
      int off = r * 256 + c4 * 8; off ^= (r & 7) << 4;
      ushort4 o;
      o.x = f2bf(v.x); o.y = f2bf(v.y); o.z = f2bf(v.z); o.w = f2bf(v.w);
      *reinterpret_cast<ushort4*>(reinterpret_cast<char*>(xs) + off) = o;
    }
  }
  __syncthreads();

  for (int p = 0; p < 3; ++p) {
    const unsigned short* Wg = Wc + ((size_t)(p * H + h) << 14);
    f32x4 acc[2][8];
#pragma unroll
    for (int m = 0; m < 2; ++m)
#pragma unroll
      for (int n = 0; n < 8; ++n) acc[m][n] = {0.f, 0.f, 0.f, 0.f};

    if (p < 2) {
#pragma unroll
      for (int kk = 0; kk < 4; ++kk) {
        bf16x8 a[2], bfr[8];
#pragma unroll
        for (int m = 0; m < 2; ++m)
          a[m] = *reinterpret_cast<const bf16x8*>(Wg + (wid * 32 + m * 16 + lr) * 128 + kk * 32 + lk * 8);
#pragma unroll
        for (int n = 0; n < 8; ++n) bfr[n] = lds_frag(xs, n * 16 + lr, kk * 64 + lk * 16, 256);
#pragma unroll
        for (int m = 0; m < 2; ++m)
#pragma unroll
          for (int n = 0; n < 8; ++n)
            acc[m][n] = __builtin_amdgcn_mfma_f32_16x16x32_bf16(a[m], bfr[n], acc[m][n], 0, 0, 0);
      }
      const float bs = (p == 0) ? QSCALE : 1.0f;
      const float* bias = ((p == 0) ? bq : bk) + h * DH;
      unsigned short* dst = ((p == 0) ? Qp : Kp);
#pragma unroll
      for (int m = 0; m < 2; ++m) {
        const int d0 = wid * 32 + m * 16 + lk * 4;
        const float4 bb = *reinterpret_cast<const float4*>(bias + d0);
#pragma unroll
        for (int n = 0; n < 8; ++n) {
          const int tok = mt * 128 + n * 16 + lr;
          const int b = tok >> 10, si = tok & 1023;
          ushort4 o;
          o.x = f2bf(acc[m][n][0] + bb.x * bs);
          o.y = f2bf(acc[m][n][1] + bb.y * bs);
          o.z = f2bf(acc[m][n][2] + bb.z * bs);
          o.w = f2bf(acc[m][n][3] + bb.w * bs);
          *reinterpret_cast<ushort4*>(dst + ((size_t)(b * H + h) * SS + si) * DH + d0) = o;
        }
      }
    } else {
#pragma unroll
      for (int kk = 0; kk < 4; ++kk) {
        bf16x8 a[2], bfr[8];
#pragma unroll
        for (int m = 0; m < 2; ++m) a[m] = lds_frag(xs, wid * 32 + m * 16 + lr, kk * 64 + lk * 16, 256);
#pragma unroll
        for (int n = 0; n < 8; ++n)
          bfr[n] = *reinterpret_cast<const bf16x8*>(Wg + (n * 16 + lr) * 128 + kk * 32 + lk * 8);
#pragma unroll
        for (int m = 0; m < 2; ++m)
#pragma unroll
          for (int n = 0; n < 8; ++n)
            acc[m][n] = __builtin_amdgcn_mfma_f32_16x16x32_bf16(a[m], bfr[n], acc[m][n], 0, 0, 0);
      }
      const float* bias = bv + h * DH;
#pragma unroll
      for (int n = 0; n < 8; ++n) {
        const int d = n * 16 + lr;
        const float bb = bias[d];
#pragma unroll
        for (int m = 0; m < 2; ++m) {
          const int tok0 = mt * 128 + wid * 32 + m * 16 + lk * 4;
          const int b = tok0 >> 10, s0 = tok0 & 1023;
          ushort4 o;
          o.x = f2bf(acc[m][n][0] + bb);
          o.y = f2bf(acc[m][n][1] + bb);
          o.z = f2bf(acc[m][n][2] + bb);
          o.w = f2bf(acc[m][n][3] + bb);
          *reinterpret_cast<ushort4*>(Vt + ((size_t)(b * H + h) * DH + d) * SS + s0) = o;
        }
      }
    }
  }
}

// ---------------- Kernel C: flash attention, no LDS, no barriers ----------------
// Swapped QK^T: sacc = mfma(K,Q) -> lane owns P[k-chunk][q=lane&15].
// In-register softmax + cvt_pk/shfl transpose to PV A-fragment.
__global__ __launch_bounds__(256, 2) void attn_kernel(
    const unsigned short* __restrict__ Qp, const unsigned short* __restrict__ Kp,
    const unsigned short* __restrict__ Vt, float* __restrict__ outp) {
  // XCD-clustered decode: 8 q-tile blocks of each bh land on one XCD (K+V of 8 bh = 4MB = one L2)
  const int id = blockIdx.x;
  const int xcd = id & 7, slot = id >> 3;
  const int bh = xcd * 8 + (slot >> 3);
  const int qt = slot & 7;
  const int b = bh >> 3, h = bh & 7;
  const int tid = threadIdx.x, wid = tid >> 6, lane = tid & 63;
  const int lr = lane & 15, lk = lane >> 4;

  // Q fragments in registers (B-operand: col=lane&15 is q, k-dim is d)
  bf16x8 qa[2][4];
  {
    const unsigned short* Qg = Qp + (size_t)bh * (SS * DH) + (size_t)(qt * 128 + wid * 32) * DH;
#pragma unroll
    for (int m = 0; m < 2; ++m)
#pragma unroll
      for (int kk = 0; kk < 4; ++kk)
        qa[m][kk] = *reinterpret_cast<const bf16x8*>(Qg + (m * 16 + lr) * DH + kk * 32 + lk * 8);
  }

  const unsigned short* Kg = Kp + (size_t)bh * (SS * DH);
  const unsigned short* Vg = Vt + (size_t)bh * (DH * SS);

  f32x4 oacc[2][8];
#pragma unroll
  for (int m = 0; m < 2; ++m)
#pragma unroll
    for (int n = 0; n < 8; ++n) oacc[m][n] = {0.f, 0.f, 0.f, 0.f};
  float mrow[2] = {-1e30f, -1e30f};  // per-lane: q = (wave base) + m*16 + (lane&15)
  float lrow[2] = {0.f, 0.f};

  for (int kt = 0; kt < 16; ++kt) {
    const unsigned short* kb = Kg + (size_t)kt * 64 * DH;

    // S^T = K Q^T : sacc[m][n] holds k = n*16 + lk*4 + r, q = m*16 + lr (scores already in log2 units)
    f32x4 sacc[2][4];
#pragma unroll
    for (int m = 0; m < 2; ++m)
#pragma unroll
      for (int n = 0; n < 4; ++n) sacc[m][n] = {0.f, 0.f, 0.f, 0.f};
#pragma unroll
    for (int kk = 0; kk < 4; ++kk) {
      bf16x8 kf[4];
#pragma unroll
      for (int n = 0; n < 4; ++n)
        kf[n] = *reinterpret_cast<const bf16x8*>(kb + (n * 16 + lr) * DH + kk * 32 + lk * 8);
#pragma unroll
      for (int n = 0; n < 4; ++n)
#pragma unroll
        for (int m = 0; m < 2; ++m)
          sacc[m][n] = __builtin_amdgcn_mfma_f32_16x16x32_bf16(kf[n], qa[m][kk], sacc[m][n], 0, 0, 0);
    }

    // online softmax, defer-max (THR=8 in log2 units)
    float mx[2];
#pragma unroll
    for (int m = 0; m < 2; ++m) {
      float a = fmaxf(fmaxf(sacc[m][0][0], sacc[m][0][1]), fmaxf(sacc[m][0][2], sacc[m][0][3]));
      float c = fmaxf(fmaxf(sacc[m][1][0], sacc[m][1][1]), fmaxf(sacc[m][1][2], sacc[m][1][3]));
      float d = fmaxf(fmaxf(sacc[m][2][0], sacc[m][2][1]), fmaxf(sacc[m][2][2], sacc[m][2][3]));
      float e = fmaxf(fmaxf(sacc[m][3][0], sacc[m][3][1]), fmaxf(sacc[m][3][2], sacc[m][3][3]));
      float v = fmaxf(fmaxf(a, c), fmaxf(d, e));
      v = fmaxf(v, __shfl_xor(v, 16));
      v = fmaxf(v, __shfl_xor(v, 32));
      mx[m] = v;
    }
    const int okf = (mx[0] <= mrow[0] + 8.f) && (mx[1] <= mrow[1] + 8.f);
    if (__all(okf)) {
#pragma unroll
      for (int m = 0; m < 2; ++m) {
        float s = 0.f;
#pragma unroll
        for (int n = 0; n < 4; ++n)
#pragma unroll
          for (int r = 0; r < 4; ++r) {
            const float pv = exp2f(sacc[m][n][r] - mrow[m]);
            sacc[m][n][r] = pv;
            s += pv;
          }
        s += __shfl_xor(s, 16);
        s += __shfl_xor(s, 32);
        lrow[m] += s;
      }
    } else {
#pragma unroll
      for (int m = 0; m < 2; ++m) {
        const float mnew = fmaxf(mrow[m], mx[m]);
        const float alpha = exp2f(mrow[m] - mnew);
        mrow[m] = mnew;
        float s = 0.f;
#pragma unroll
        for (int n = 0; n < 4; ++n)
#pragma unroll
          for (int r = 0; r < 4; ++r) {
            const float pv = exp2f(sacc[m][n][r] - mnew);
            sacc[m][n][r] = pv;
            s += pv;
          }
        s += __shfl_xor(s, 16);
        s += __shfl_xor(s, 32);
        lrow[m] = lrow[m] * alpha + s;
        // rescale O rows: oacc row q-local = lk*4 + r; alpha lives on lane lr == lk*4+r
#pragma unroll
        for (int r = 0; r < 4; ++r) {
          const float ar = __shfl(alpha, lk * 4 + r);
#pragma unroll
          for (int n = 0; n < 8; ++n) oacc[m][n][r] *= ar;
        }
      }
    }

    // P (f32, col=q layout) -> bf16 A-fragment (row=q layout), fully in-register
    bf16x8 pa[2][2];
#pragma unroll
    for (int m = 0; m < 2; ++m) {
      unsigned int pk0[4], pk1[4];
#pragma unroll
      for (int n = 0; n < 4; ++n) {
        pk0[n] = cvtpk_bf16(sacc[m][n][0], sacc[m][n][1]);
        pk1[n] = cvtpk_bf16(sacc[m][n][2], sacc[m][n][3]);
      }
#pragma unroll
      for (int kk2 = 0; kk2 < 2; ++kk2) {
        unsigned int w[4];
#pragma unroll
        for (int j = 0; j < 4; ++j) {
          const unsigned int lo = (j & 1) ? pk1[2 * kk2] : pk0[2 * kk2];
          const unsigned int hi = (j & 1) ? pk1[2 * kk2 + 1] : pk0[2 * kk2 + 1];
          const unsigned int sel = (lk & 2) ? hi : lo;
          const int srcl = lr + 16 * ((lk & 1) * 2 + (j >> 1));
          w[j] = (unsigned int)__shfl((int)sel, srcl);
        }
        uint4 t; t.x = w[0]; t.y = w[1]; t.z = w[2]; t.w = w[3];
        pa[m][kk2] = __builtin_bit_cast(bf16x8, t);
      }
    }

    // O += P V : B-operand = V^T frags direct from global (col=d, k=kv contiguous)
    const unsigned short* vb = Vg + kt * 64;
#pragma unroll
    for (int kk2 = 0; kk2 < 2; ++kk2) {
#pragma unroll
      for (int n = 0; n < 8; ++n) {
        const bf16x8 vf = *reinterpret_cast<const bf16x8*>(vb + (size_t)(n * 16 + lr) * SS + kk2 * 32 + lk * 8);
#pragma unroll
        for (int m = 0; m < 2; ++m)
          oacc[m][n] = __builtin_amdgcn_mfma_f32_16x16x32_bf16(pa[m][kk2], vf, oacc[m][n], 0, 0, 0);
      }
    }
  }

  // epilogue: normalize and store f32
#pragma unroll
  for (int m = 0; m < 2; ++m)
#pragma unroll
    for (int r = 0; r < 4; ++r) {
      const float lsum = __shfl(lrow[m], lk * 4 + r);
      const float inv = 1.f / lsum;
      const int srow = qt * 128 + wid * 32 + m * 16 + lk * 4 + r;
      float* og = outp + ((size_t)b * SS + srow) * DD + h * DH;
#pragma unroll
      for (int n = 0; n < 8; ++n) og[n * 16 + lr] = oacc[m][n][r] * inv;
    }
}

extern "C" void kernel_launch(void* const* d_in, const int* in_sizes, int n_in,
                              void* d_out, int out_size, void* d_ws, size_t ws_size,
                              hipStream_t stream) {
  const float* x  = (const float*)d_in[0];
  const float* Uq = (const float*)d_in[1];
  const float* Vq = (const float*)d_in[2];
  const float* bq = (const float*)d_in[3];
  const float* Uk = (const float*)d_in[4];
  const float* Vk = (const float*)d_in[5];
  const float* bk = (const float*)d_in[6];
  const float* Uv = (const float*)d_in[7];
  const float* Vv = (const float*)d_in[8];
  const float* bv = (const float*)d_in[9];
  float* outp = (float*)d_out;

  unsigned short* Wc = (unsigned short*)d_ws;                     // 3*8*128*128 bf16
  unsigned short* Qp = Wc + (size_t)3 * H * DH * DH;              // [b,h,s,d] bf16 (pre-scaled by QSCALE)
  unsigned short* Kp = Qp + (size_t)BB * H * SS * DH;             // [b,h,s,d] bf16
  unsigned short* Vt = Kp + (size_t)BB * H * SS * DH;             // [b,h,d,s] bf16

  wcomb_kernel<<<dim3(24), dim3(256), 0, stream>>>(Uq, Vq, Uk, Vk, Uv, Vv, Wc);
  proj_kernel<<<dim3(64, 8), dim3(256), 0, stream>>>(x, Wc, bq, bk, bv, Qp, Kp, Vt);
  attn_kernel<<<dim3(512), dim3(256), 0, stream>>>(Qp, Kp, Vt, outp);
}

// Round 3
// 215.014 us; speedup vs baseline: 1.6294x; 1.2130x over previous
//
#include <hip/hip_runtime.h>
#include <cstdint>
#include <cstddef>

#define H 8
#define DH 128
#define RNK 32
#define SS 1024
#define BB 8
#define DD 1024

typedef __bf16 bf16x8 __attribute__((ext_vector_type(8)));
typedef float f32x4 __attribute__((ext_vector_type(4)));

// log2(e)/sqrt(DH): folded into Wq and bq so QK^T is already in log2 domain.
#define QSCALE (1.4426950408889634f / 11.313708498984761f)

__device__ __forceinline__ unsigned short f2bf(float f) {
  unsigned int u = __builtin_bit_cast(unsigned int, f);
  return (unsigned short)((u + 0x7FFFu + ((u >> 16) & 1u)) >> 16);
}

__device__ __forceinline__ unsigned int cvtpk_bf16(float lo, float hi) {
  unsigned int r;
  asm("v_cvt_pk_bf16_f32 %0, %1, %2" : "=v"(r) : "v"(lo), "v"(hi));
  return r;
}

// async global->LDS, 16B per lane; LDS dest = wave-uniform base + lane*16
__device__ __forceinline__ void gload_lds16(const void* g, void* l) {
  __builtin_amdgcn_global_load_lds((const __attribute__((address_space(1))) void*)g,
                                   (__attribute__((address_space(3))) void*)l, 16, 0, 0);
}

// Swizzled LDS fragment read: 8 contiguous bf16 at (row, kbyte), row-XOR swizzle
__device__ __forceinline__ bf16x8 lds_frag(const unsigned short* base, int row, int kbyte, int rowbytes) {
  int off = row * rowbytes + kbyte;
  off ^= (row & 7) << 4;
  return *reinterpret_cast<const bf16x8*>(reinterpret_cast<const char*>(base) + off);
}

// ---------------- Kernel A: W = U @ V per (proj, head), f32 -> bf16 ----------------
__global__ __launch_bounds__(256) void wcomb_kernel(
    const float* __restrict__ Uq, const float* __restrict__ Vq,
    const float* __restrict__ Uk, const float* __restrict__ Vk,
    const float* __restrict__ Uv, const float* __restrict__ Vv,
    unsigned short* __restrict__ Wc) {
  const int p = blockIdx.x / H, h = blockIdx.x % H;
  const float* U = (p == 0) ? Uq : ((p == 1) ? Uk : Uv);
  const float* V = (p == 0) ? Vq : ((p == 1) ? Vk : Vv);
  const float scale = (p == 0) ? QSCALE : 1.0f;
  U += (size_t)h * DH * RNK;
  V += (size_t)h * RNK * DH;
  __shared__ float Vl[RNK * DH];
  for (int i = threadIdx.x; i < RNK * DH; i += 256) Vl[i] = V[i];
  __syncthreads();
  const int dout = threadIdx.x >> 1;
  const int di0 = (threadIdx.x & 1) * 64;
  float Ur[RNK];
#pragma unroll
  for (int r = 0; r < RNK; ++r) Ur[r] = U[dout * RNK + r] * scale;
  unsigned short* outp = Wc + ((size_t)(p * H + h) * DH + dout) * DH + di0;
  for (int di4 = 0; di4 < 16; ++di4) {
    float4 acc = {0.f, 0.f, 0.f, 0.f};
#pragma unroll
    for (int r = 0; r < RNK; ++r) {
      const float4 v = *reinterpret_cast<const float4*>(&Vl[r * DH + di0 + di4 * 4]);
      acc.x += Ur[r] * v.x; acc.y += Ur[r] * v.y;
      acc.z += Ur[r] * v.z; acc.w += Ur[r] * v.w;
    }
    ushort4 o;
    o.x = f2bf(acc.x); o.y = f2bf(acc.y); o.z = f2bf(acc.z); o.w = f2bf(acc.w);
    *reinterpret_cast<ushort4*>(outp + di4 * 4) = o;
  }
}

// ---------------- Kernel B: fused QKV projection, coalesced epilogue ----------------
__global__ __launch_bounds__(256, 2) void proj_kernel(
    const float* __restrict__ x, const unsigned short* __restrict__ Wc,
    const float* __restrict__ bq, const float* __restrict__ bk, const float* __restrict__ bv,
    unsigned short* __restrict__ Qp, unsigned short* __restrict__ Kp, unsigned short* __restrict__ Vt) {
  const int mt = blockIdx.x;  // 64 token tiles of 128
  const int h  = blockIdx.y;  // 8
  const int tid = threadIdx.x;
  const int wid = tid >> 6;
  const int lane = tid & 63;
  const int lr = lane & 15, lk = lane >> 4;
  const int bb_ = mt >> 3;  // batch index of this token tile

  __shared__ unsigned short xs[128 * 128];
  __shared__ unsigned short ot[128 * 128];

  { // stage x tile: 128 tokens x 128 dims, f32 -> bf16, swizzled
    const float* xb = x + (size_t)(mt * 128) * DD + h * DH;
    const int c4 = tid & 31, r0 = tid >> 5;
#pragma unroll
    for (int i = 0; i < 16; ++i) {
      const int r = r0 + i * 8;
      const float4 v = *reinterpret_cast<const float4*>(xb + (size_t)r * DD + c4 * 4);
      int off = r * 256 + c4 * 8; off ^= (r & 7) << 4;
      ushort4 o;
      o.x = f2bf(v.x); o.y = f2bf(v.y); o.z = f2bf(v.z); o.w = f2bf(v.w);
      *reinterpret_cast<ushort4*>(reinterpret_cast<char*>(xs) + off) = o;
    }
  }
  __syncthreads();

  for (int p = 0; p < 3; ++p) {
    const unsigned short* Wg = Wc + ((size_t)(p * H + h) << 14);
    f32x4 acc[2][8];
#pragma unroll
    for (int m = 0; m < 2; ++m)
#pragma unroll
      for (int n = 0; n < 8; ++n) acc[m][n] = {0.f, 0.f, 0.f, 0.f};

    if (p < 2) {
      // A=W (rows d), B=x (cols token): C col=token, row=d
#pragma unroll
      for (int kk = 0; kk < 4; ++kk) {
        bf16x8 a[2], bfr[8];
#pragma unroll
        for (int m = 0; m < 2; ++m)
          a[m] = *reinterpret_cast<const bf16x8*>(Wg + (wid * 32 + m * 16 + lr) * 128 + kk * 32 + lk * 8);
#pragma unroll
        for (int n = 0; n < 8; ++n) bfr[n] = lds_frag(xs, n * 16 + lr, kk * 64 + lk * 16, 256);
#pragma unroll
        for (int m = 0; m < 2; ++m)
#pragma unroll
          for (int n = 0; n < 8; ++n)
            acc[m][n] = __builtin_amdgcn_mfma_f32_16x16x32_bf16(a[m], bfr[n], acc[m][n], 0, 0, 0);
      }
      __syncthreads();  // prior p's store-phase reads of ot complete
      const float bs = (p == 0) ? QSCALE : 1.0f;
      const float* bias = ((p == 0) ? bq : bk) + h * DH;
      // out-tile [token][d], swizzled
#pragma unroll
      for (int m = 0; m < 2; ++m) {
        const int d0 = wid * 32 + m * 16 + lk * 4;
        const float4 bbv = *reinterpret_cast<const float4*>(bias + d0);
#pragma unroll
        for (int n = 0; n < 8; ++n) {
          const int token = n * 16 + lr;
          int off = token * 256 + d0 * 2; off ^= (token & 7) << 4;
          ushort4 o;
          o.x = f2bf(acc[m][n][0] + bbv.x * bs);
          o.y = f2bf(acc[m][n][1] + bbv.y * bs);
          o.z = f2bf(acc[m][n][2] + bbv.z * bs);
          o.w = f2bf(acc[m][n][3] + bbv.w * bs);
          *reinterpret_cast<ushort4*>(reinterpret_cast<char*>(ot) + off) = o;
        }
      }
      __syncthreads();
      // coalesced store: rows = tokens
      unsigned short* dstb = ((p == 0) ? Qp : Kp) + ((size_t)(bb_ * H + h) * SS + (mt & 7) * 128) * DH;
#pragma unroll
      for (int it = 0; it < 8; ++it) {
        const int idx = tid + it * 256;
        const int row = idx >> 4, chunk = idx & 15;
        const int off = row * 256 + ((chunk * 16) ^ ((row & 7) << 4));
        const uint4 v = *reinterpret_cast<const uint4*>(reinterpret_cast<const char*>(ot) + off);
        *reinterpret_cast<uint4*>(dstb + (size_t)row * DH + chunk * 8) = v;
      }
    } else {
      // A=x (rows token), B=W (cols d): C col=d, row=token
#pragma unroll
      for (int kk = 0; kk < 4; ++kk) {
        bf16x8 a[2], bfr[8];
#pragma unroll
        for (int m = 0; m < 2; ++m) a[m] = lds_frag(xs, wid * 32 + m * 16 + lr, kk * 64 + lk * 16, 256);
#pragma unroll
        for (int n = 0; n < 8; ++n)
          bfr[n] = *reinterpret_cast<const bf16x8*>(Wg + (n * 16 + lr) * 128 + kk * 32 + lk * 8);
#pragma unroll
        for (int m = 0; m < 2; ++m)
#pragma unroll
          for (int n = 0; n < 8; ++n)
            acc[m][n] = __builtin_amdgcn_mfma_f32_16x16x32_bf16(a[m], bfr[n], acc[m][n], 0, 0, 0);
      }
      __syncthreads();
      const float* bias = bv + h * DH;
      // out-tile [d][token], swizzled
#pragma unroll
      for (int n = 0; n < 8; ++n) {
        const int d = n * 16 + lr;
        const float bbs = bias[d];
#pragma unroll
        for (int m = 0; m < 2; ++m) {
          const int t0 = wid * 32 + m * 16 + lk * 4;
          int off = d * 256 + t0 * 2; off ^= (d & 7) << 4;
          ushort4 o;
          o.x = f2bf(acc[m][n][0] + bbs);
          o.y = f2bf(acc[m][n][1] + bbs);
          o.z = f2bf(acc[m][n][2] + bbs);
          o.w = f2bf(acc[m][n][3] + bbs);
          *reinterpret_cast<ushort4*>(reinterpret_cast<char*>(ot) + off) = o;
        }
      }
      __syncthreads();
      // coalesced store: rows = d, into V^T [b,h,d,s]
      unsigned short* dstb = Vt + ((size_t)(bb_ * H + h) * DH) * SS + (mt & 7) * 128;
#pragma unroll
      for (int it = 0; it < 8; ++it) {
        const int idx = tid + it * 256;
        const int row = idx >> 4, chunk = idx & 15;  // row = d
        const int off = row * 256 + ((chunk * 16) ^ ((row & 7) << 4));
        const uint4 v = *reinterpret_cast<const uint4*>(reinterpret_cast<const char*>(ot) + off);
        *reinterpret_cast<uint4*>(dstb + (size_t)row * SS + chunk * 8) = v;
      }
    }
  }
}

// ---------------- Kernel C: flash attention, LDS-staged K/V, 1 barrier/tile ----------------
__global__ __launch_bounds__(256, 2) void attn_kernel(
    const unsigned short* __restrict__ Qp, const unsigned short* __restrict__ Kp,
    const unsigned short* __restrict__ Vt, float* __restrict__ outp) {
  const int id = blockIdx.x;
  const int xcd = id & 7;
  const int bh = xcd * 8 + (id >> 6);
  const int qt = (id >> 3) & 7;
  const int b = bh >> 3, h = bh & 7;
  const int tid = threadIdx.x, wid = tid >> 6, lane = tid & 63;
  const int lr = lane & 15, lk = lane >> 4;

  __shared__ unsigned short ks[2][64 * 128];   // K tile [s=64][d=128], swizzled, dbuf
  __shared__ unsigned short vs[2][128 * 64];   // V^T tile [d=128][s=64], swizzled, dbuf

  const char* Kg = (const char*)(Kp + (size_t)bh * (SS * DH));
  const char* Vg = (const char*)(Vt + (size_t)bh * (DH * SS));

  // --- staging (pre-swizzled global source; linear LDS dest) ---
  // K tile kt -> buf: 16 chunks of 1KB; wave w issues chunks w*4..w*4+3
#define STAGE_K(KT, BUF)                                                            \
  {                                                                                 \
    _Pragma("unroll")                                                               \
    for (int c4 = 0; c4 < 4; ++c4) {                                                \
      const int c = wid * 4 + c4;                                                   \
      const int row = c * 4 + (lane >> 4);                                          \
      const int colb = ((lane & 15) << 4) ^ ((row & 7) << 4);                       \
      gload_lds16(Kg + (size_t)((KT) * 64 + row) * 256 + colb,                      \
                  (char*)(ks[BUF]) + c * 1024);                                     \
    }                                                                               \
  }
  // V tile: rows d (128B each); 16 chunks of 1KB; row = c*8 + lane>>3
#define STAGE_V(KT, BUF)                                                            \
  {                                                                                 \
    _Pragma("unroll")                                                               \
    for (int c4 = 0; c4 < 4; ++c4) {                                                \
      const int c = wid * 4 + c4;                                                   \
      const int row = c * 8 + (lane >> 3);                                          \
      const int colb = ((lane & 7) << 4) ^ ((row & 7) << 4);                        \
      gload_lds16(Vg + (size_t)row * 2048 + (KT) * 128 + colb,                      \
                  (char*)(vs[BUF]) + c * 1024);                                     \
    }                                                                               \
  }

  STAGE_K(0, 0);
  STAGE_V(0, 0);

  // Q fragments in registers (B-operand: col=lane&15 is q, k-dim is d)
  bf16x8 qa[2][4];
  {
    const unsigned short* Qg = Qp + (size_t)bh * (SS * DH) + (size_t)(qt * 128 + wid * 32) * DH;
#pragma unroll
    for (int m = 0; m < 2; ++m)
#pragma unroll
      for (int kk = 0; kk < 4; ++kk)
        qa[m][kk] = *reinterpret_cast<const bf16x8*>(Qg + (m * 16 + lr) * DH + kk * 32 + lk * 8);
  }

  f32x4 oacc[2][8];
#pragma unroll
  for (int m = 0; m < 2; ++m)
#pragma unroll
    for (int n = 0; n < 8; ++n) oacc[m][n] = {0.f, 0.f, 0.f, 0.f};
  float mrow[2] = {-1e30f, -1e30f};
  float lrow[2] = {0.f, 0.f};

  for (int kt = 0; kt < 16; ++kt) {
    __syncthreads();  // drains staging of tile kt (issued a full tile ago -> ~free)
    const int cur = kt & 1;
    if (kt < 15) {
      STAGE_K(kt + 1, cur ^ 1);
      STAGE_V(kt + 1, cur ^ 1);
    }
    const unsigned short* kb = ks[cur];
    const unsigned short* vb = vs[cur];

    // S^T = K Q^T : sacc[m][n] holds k = n*16 + lk*4 + r, q = m*16 + lr (log2 units)
    f32x4 sacc[2][4];
#pragma unroll
    for (int m = 0; m < 2; ++m)
#pragma unroll
      for (int n = 0; n < 4; ++n) sacc[m][n] = {0.f, 0.f, 0.f, 0.f};
    __builtin_amdgcn_s_setprio(1);
#pragma unroll
    for (int kk = 0; kk < 4; ++kk) {
      bf16x8 kf[4];
#pragma unroll
      for (int n = 0; n < 4; ++n) kf[n] = lds_frag(kb, n * 16 + lr, kk * 64 + lk * 16, 256);
#pragma unroll
      for (int n = 0; n < 4; ++n)
#pragma unroll
        for (int m = 0; m < 2; ++m)
          sacc[m][n] = __builtin_amdgcn_mfma_f32_16x16x32_bf16(kf[n], qa[m][kk], sacc[m][n], 0, 0, 0);
    }
    __builtin_amdgcn_s_setprio(0);

    // online softmax, defer-max (THR=8 in log2 units)
    float mx[2];
#pragma unroll
    for (int m = 0; m < 2; ++m) {
      float a = fmaxf(fmaxf(sacc[m][0][0], sacc[m][0][1]), fmaxf(sacc[m][0][2], sacc[m][0][3]));
      float c = fmaxf(fmaxf(sacc[m][1][0], sacc[m][1][1]), fmaxf(sacc[m][1][2], sacc[m][1][3]));
      float d = fmaxf(fmaxf(sacc[m][2][0], sacc[m][2][1]), fmaxf(sacc[m][2][2], sacc[m][2][3]));
      float e = fmaxf(fmaxf(sacc[m][3][0], sacc[m][3][1]), fmaxf(sacc[m][3][2], sacc[m][3][3]));
      float v = fmaxf(fmaxf(a, c), fmaxf(d, e));
      v = fmaxf(v, __shfl_xor(v, 16));
      v = fmaxf(v, __shfl_xor(v, 32));
      mx[m] = v;
    }
    const int okf = (mx[0] <= mrow[0] + 8.f) && (mx[1] <= mrow[1] + 8.f);
    if (__all(okf)) {
#pragma unroll
      for (int m = 0; m < 2; ++m) {
        float s = 0.f;
#pragma unroll
        for (int n = 0; n < 4; ++n)
#pragma unroll
          for (int r = 0; r < 4; ++r) {
            const float pv = exp2f(sacc[m][n][r] - mrow[m]);
            sacc[m][n][r] = pv;
            s += pv;
          }
        s += __shfl_xor(s, 16);
        s += __shfl_xor(s, 32);
        lrow[m] += s;
      }
    } else {
#pragma unroll
      for (int m = 0; m < 2; ++m) {
        const float mnew = fmaxf(mrow[m], mx[m]);
        const float alpha = exp2f(mrow[m] - mnew);
        mrow[m] = mnew;
        float s = 0.f;
#pragma unroll
        for (int n = 0; n < 4; ++n)
#pragma unroll
          for (int r = 0; r < 4; ++r) {
            const float pv = exp2f(sacc[m][n][r] - mnew);
            sacc[m][n][r] = pv;
            s += pv;
          }
        s += __shfl_xor(s, 16);
        s += __shfl_xor(s, 32);
        lrow[m] = lrow[m] * alpha + s;
#pragma unroll
        for (int r = 0; r < 4; ++r) {
          const float ar = __shfl(alpha, lk * 4 + r);
#pragma unroll
          for (int n = 0; n < 8; ++n) oacc[m][n][r] *= ar;
        }
      }
    }

    // P (f32, col=q layout) -> bf16 A-fragment (row=q layout), fully in-register
    bf16x8 pa[2][2];
#pragma unroll
    for (int m = 0; m < 2; ++m) {
      unsigned int pk0[4], pk1[4];
#pragma unroll
      for (int n = 0; n < 4; ++n) {
        pk0[n] = cvtpk_bf16(sacc[m][n][0], sacc[m][n][1]);
        pk1[n] = cvtpk_bf16(sacc[m][n][2], sacc[m][n][3]);
      }
#pragma unroll
      for (int kk2 = 0; kk2 < 2; ++kk2) {
        unsigned int w[4];
#pragma unroll
        for (int j = 0; j < 4; ++j) {
          const unsigned int lo = (j & 1) ? pk1[2 * kk2] : pk0[2 * kk2];
          const unsigned int hi = (j & 1) ? pk1[2 * kk2 + 1] : pk0[2 * kk2 + 1];
          const unsigned int sel = (lk & 2) ? hi : lo;
          const int srcl = lr + 16 * ((lk & 1) * 2 + (j >> 1));
          w[j] = (unsigned int)__shfl((int)sel, srcl);
        }
        uint4 t; t.x = w[0]; t.y = w[1]; t.z = w[2]; t.w = w[3];
        pa[m][kk2] = __builtin_bit_cast(bf16x8, t);
      }
    }

    // O += P V : B-operand = V^T frags from LDS (col=d, k=kv contiguous)
    __builtin_amdgcn_s_setprio(1);
#pragma unroll
    for (int kk2 = 0; kk2 < 2; ++kk2) {
#pragma unroll
      for (int n = 0; n < 8; ++n) {
        const bf16x8 vf = lds_frag(vb, n * 16 + lr, kk2 * 64 + lk * 16, 128);
#pragma unroll
        for (int m = 0; m < 2; ++m)
          oacc[m][n] = __builtin_amdgcn_mfma_f32_16x16x32_bf16(pa[m][kk2], vf, oacc[m][n], 0, 0, 0);
      }
    }
    __builtin_amdgcn_s_setprio(0);
  }

  // epilogue: normalize and store f32
#pragma unroll
  for (int m = 0; m < 2; ++m)
#pragma unroll
    for (int r = 0; r < 4; ++r) {
      const float lsum = __shfl(lrow[m], lk * 4 + r);
      const float inv = 1.f / lsum;
      const int srow = qt * 128 + wid * 32 + m * 16 + lk * 4 + r;
      float* og = outp + ((size_t)b * SS + srow) * DD + h * DH;
#pragma unroll
      for (int n = 0; n < 8; ++n) og[n * 16 + lr] = oacc[m][n][r] * inv;
    }
}

extern "C" void kernel_launch(void* const* d_in, const int* in_sizes, int n_in,
                              void* d_out, int out_size, void* d_ws, size_t ws_size,
                              hipStream_t stream) {
  const float* x  = (const float*)d_in[0];
  const float* Uq = (const float*)d_in[1];
  const float* Vq = (const float*)d_in[2];
  const float* bq = (const float*)d_in[3];
  const float* Uk = (const float*)d_in[4];
  const float* Vk = (const float*)d_in[5];
  const float* bk = (const float*)d_in[6];
  const float* Uv = (const float*)d_in[7];
  const float* Vv = (const float*)d_in[8];
  const float* bv = (const float*)d_in[9];
  float* outp = (float*)d_out;

  unsigned short* Wc = (unsigned short*)d_ws;                     // 3*8*128*128 bf16
  unsigned short* Qp = Wc + (size_t)3 * H * DH * DH;              // [b,h,s,d] bf16 (pre-scaled)
  unsigned short* Kp = Qp + (size_t)BB * H * SS * DH;             // [b,h,s,d] bf16
  unsigned short* Vt = Kp + (size_t)BB * H * SS * DH;             // [b,h,d,s] bf16

  wcomb_kernel<<<dim3(24), dim3(256), 0, stream>>>(Uq, Vq, Uk, Vk, Uv, Vv, Wc);
  proj_kernel<<<dim3(64, 8), dim3(256), 0, stream>>>(x, Wc, bq, bk, bv, Qp, Kp, Vt);
  attn_kernel<<<dim3(512), dim3(256), 0, stream>>>(Qp, Kp, Vt, outp);
}